// Round 1
// baseline (816.199 us; speedup 1.0000x reference)
//
#include <hip/hip_runtime.h>
#include <math.h>

#define DIMK 2048
#define NEMB 16384
#define NB 256
#define NR2 1536          // 256*6 neighbor rows
#define NBLK 128          // n-blocks in sims gemm
#define INV_BETA 20.0f
#define NEG_INF (-3.0e38f)

typedef short short8 __attribute__((ext_vector_type(8)));
typedef float f32x4 __attribute__((ext_vector_type(4)));

__device__ __forceinline__ unsigned short f2bf(float f) {
  unsigned u = __float_as_uint(f);
  u += 0x7fffu + ((u >> 16) & 1u);
  return (unsigned short)(u >> 16);
}

__device__ __forceinline__ void ins6(float x, float v[6]) {
  if (x > v[5]) {
    v[5] = x;
#pragma unroll
    for (int j = 5; j > 0; j--) {
      if (v[j] > v[j - 1]) { float tmp = v[j]; v[j] = v[j - 1]; v[j - 1] = tmp; }
    }
  }
}

__global__ __launch_bounds__(256) void cvt_kernel(const float* __restrict__ src,
                                                  unsigned short* __restrict__ dst, int n4) {
  int i = blockIdx.x * 256 + threadIdx.x;
  if (i < n4) {
    float4 f = ((const float4*)src)[i];
    ushort4 o;
    o.x = f2bf(f.x); o.y = f2bf(f.y); o.z = f2bf(f.z); o.w = f2bf(f.w);
    ((ushort4*)dst)[i] = o;
  }
}

union SMemT {
  struct { unsigned short A[128 * 40]; unsigned short Bm[128 * 40]; } st;
  struct { float ct[64 * 132]; float p6[64 * 24]; } ep;
};

// MODE 0: C = X(256xK) * em^T -> logits*20 (fp32 out)
// MODE 1: C = em[nidx](1536xK) * em^T -> per-(row,128col-block) top-6 partials
template <int MODE>
__global__ __launch_bounds__(256, 2) void gemm_kernel(
    const unsigned short* __restrict__ Abase, const unsigned short* __restrict__ Bbase,
    const int* __restrict__ nidx, float* __restrict__ outC, float* __restrict__ part6) {
  __shared__ SMemT sm;
  __shared__ int rowIdxSh[128];
  int t = threadIdx.x;
  int lane = t & 63, wave = t >> 6;
  int quad = lane >> 4, l16 = lane & 15;
  int wr = wave >> 1, wc = wave & 1;
  int bn = blockIdx.x, bm = blockIdx.y;

  if constexpr (MODE == 1) {
    if (t < 128) rowIdxSh[t] = nidx[bm * 128 + t];
    __syncthreads();
  }
  int sr = t >> 2;          // 0..63
  int sc = (t & 3) * 8;     // 0,8,16,24
  size_t aOff0, aOff1;
  if constexpr (MODE == 0) {
    aOff0 = (size_t)(bm * 128 + sr) * DIMK;
    aOff1 = (size_t)(bm * 128 + sr + 64) * DIMK;
  } else {
    aOff0 = (size_t)rowIdxSh[sr] * DIMK;
    aOff1 = (size_t)rowIdxSh[sr + 64] * DIMK;
  }
  size_t bOff0 = (size_t)(bn * 128 + sr) * DIMK;
  size_t bOff1 = (size_t)(bn * 128 + sr + 64) * DIMK;

  f32x4 acc[4][4];
#pragma unroll
  for (int mi = 0; mi < 4; mi++)
#pragma unroll
    for (int ni = 0; ni < 4; ni++) acc[mi][ni] = (f32x4)0.0f;

  for (int k0 = 0; k0 < DIMK; k0 += 32) {
    int4 a0 = *(const int4*)(Abase + aOff0 + k0 + sc);
    int4 a1 = *(const int4*)(Abase + aOff1 + k0 + sc);
    int4 b0 = *(const int4*)(Bbase + bOff0 + k0 + sc);
    int4 b1 = *(const int4*)(Bbase + bOff1 + k0 + sc);
    __syncthreads();
    *(int4*)&sm.st.A[sr * 40 + sc] = a0;
    *(int4*)&sm.st.A[(sr + 64) * 40 + sc] = a1;
    *(int4*)&sm.st.Bm[sr * 40 + sc] = b0;
    *(int4*)&sm.st.Bm[(sr + 64) * 40 + sc] = b1;
    __syncthreads();
    short8 af[4], bfv[4];
#pragma unroll
    for (int mi = 0; mi < 4; mi++)
      af[mi] = *(const short8*)&sm.st.A[(wr * 64 + mi * 16 + l16) * 40 + quad * 8];
#pragma unroll
    for (int ni = 0; ni < 4; ni++)
      bfv[ni] = *(const short8*)&sm.st.Bm[(wc * 64 + ni * 16 + l16) * 40 + quad * 8];
#pragma unroll
    for (int mi = 0; mi < 4; mi++)
#pragma unroll
      for (int ni = 0; ni < 4; ni++)
        acc[mi][ni] = __builtin_amdgcn_mfma_f32_16x16x32_bf16(af[mi], bfv[ni], acc[mi][ni], 0, 0, 0);
  }

  if constexpr (MODE == 0) {
#pragma unroll
    for (int mi = 0; mi < 4; mi++) {
      int row = bm * 128 + wr * 64 + mi * 16 + quad * 4;
#pragma unroll
      for (int ni = 0; ni < 4; ni++) {
        int col = bn * 128 + wc * 64 + ni * 16 + l16;
#pragma unroll
        for (int rr = 0; rr < 4; rr++)
          outC[(size_t)(row + rr) * NEMB + col] = acc[mi][ni][rr] * INV_BETA;
      }
    }
  } else {
    __syncthreads();  // all LDS staging reads done before union reuse
#pragma unroll
    for (int ph = 0; ph < 2; ph++) {
      if (wr == ph) {
#pragma unroll
        for (int mi = 0; mi < 4; mi++)
#pragma unroll
          for (int ni = 0; ni < 4; ni++)
#pragma unroll
            for (int rr = 0; rr < 4; rr++)
              sm.ep.ct[(mi * 16 + quad * 4 + rr) * 132 + wc * 64 + ni * 16 + l16] = acc[mi][ni][rr];
      }
      __syncthreads();
      {
        int srow = t >> 2, sseg = t & 3;
        float v[6] = {NEG_INF, NEG_INF, NEG_INF, NEG_INF, NEG_INF, NEG_INF};
        const float* basep = &sm.ep.ct[srow * 132 + sseg * 32];
        for (int i = 0; i < 32; i++) ins6(basep[i], v);
#pragma unroll
        for (int j = 0; j < 6; j++) sm.ep.p6[srow * 24 + sseg * 6 + j] = v[j];
      }
      __syncthreads();
      if (t < 64) {
        float v[6] = {NEG_INF, NEG_INF, NEG_INF, NEG_INF, NEG_INF, NEG_INF};
        const float* pp = &sm.ep.p6[t * 24];
        for (int i = 0; i < 24; i++) ins6(pp[i], v);
        int rg = bm * 128 + ph * 64 + t;
        float* dst = part6 + ((size_t)rg * NBLK + bn) * 6;
#pragma unroll
        for (int j = 0; j < 6; j++) dst[j] = v[j];
      }
      __syncthreads();
    }
  }
}

__global__ __launch_bounds__(256) void rowstats_kernel(
    const float* __restrict__ logits, float* __restrict__ topv,
    int* __restrict__ topi, float* __restrict__ lse) {
  int m = blockIdx.x, t = threadIdx.x;
  const float* row = logits + (size_t)m * NEMB;
  __shared__ float sv[256];
  __shared__ int si[256];
  int chosen[6]; float chv[6];
  for (int pass = 0; pass < 6; pass++) {
    float bv = NEG_INF; int bi = 0x7fffffff;
    for (int i = t; i < NEMB; i += 256) {
      bool skip = false;
#pragma unroll
      for (int j = 0; j < 6; j++)
        if (j < pass && i == chosen[j]) skip = true;
      float v = row[i];
      if (!skip && (v > bv || (v == bv && i < bi))) { bv = v; bi = i; }
    }
    sv[t] = bv; si[t] = bi;
    __syncthreads();
    for (int s = 128; s > 0; s >>= 1) {
      if (t < s) {
        if (sv[t + s] > sv[t] || (sv[t + s] == sv[t] && si[t + s] < si[t])) {
          sv[t] = sv[t + s]; si[t] = si[t + s];
        }
      }
      __syncthreads();
    }
    chosen[pass] = si[0]; chv[pass] = sv[0];
    __syncthreads();
  }
  float mx = chv[0];
  float ssum = 0.f;
  for (int i = t; i < NEMB; i += 256) ssum += expf(row[i] - mx);
  sv[t] = ssum; __syncthreads();
  for (int s = 128; s > 0; s >>= 1) { if (t < s) sv[t] += sv[t + s]; __syncthreads(); }
  if (t == 0) {
    lse[m] = mx + logf(sv[0]);
#pragma unroll
    for (int j = 0; j < 6; j++) { topv[m * 6 + j] = chv[j]; topi[m * 6 + j] = chosen[j]; }
  }
}

// exact fp32 dot: sa[r] = em[topi[r]] . em[anchor(m=r/6)]
__global__ __launch_bounds__(256) void sa_kernel(const float* __restrict__ em,
                                                 const int* __restrict__ topi,
                                                 float* __restrict__ sa) {
  int gid = blockIdx.x * 256 + threadIdx.x;
  int w = gid >> 6, lane = gid & 63;
  if (w >= NR2) return;
  int m = w / 6;
  int i = topi[w], a = topi[m * 6];
  const float* ei = em + (size_t)i * DIMK;
  const float* ea = em + (size_t)a * DIMK;
  float s = 0.f;
  for (int d = lane; d < DIMK; d += 64) s += ei[d] * ea[d];
#pragma unroll
  for (int off = 32; off > 0; off >>= 1) s += __shfl_down(s, off, 64);
  if (lane == 0) sa[w] = s;
}

__global__ __launch_bounds__(256) void stage2_kernel(const float* __restrict__ part6,
                                                     const float* __restrict__ sa,
                                                     int* __restrict__ recip) {
  int r = blockIdx.x * 256 + threadIdx.x;
  if (r >= NR2) return;
  const float* p = part6 + (size_t)r * (NBLK * 6);
  float v[6] = {NEG_INF, NEG_INF, NEG_INF, NEG_INF, NEG_INF, NEG_INF};
  for (int i = 0; i < NBLK * 6; i++) ins6(p[i], v);
  recip[r] = (sa[r] >= v[5]) ? 1 : 0;
}

__global__ __launch_bounds__(256) void final_kernel(
    const float* __restrict__ logits, const float* __restrict__ topv,
    const int* __restrict__ topi, const float* __restrict__ lse_arr,
    const int* __restrict__ recip, const int* __restrict__ targets,
    float* __restrict__ out) {
  int m = threadIdx.x;
  float lse = lse_arr[m];
  int tgt = targets[m];
  float tl = logits[(size_t)m * NEMB + tgt];
  float beta = 0.f, Ps = 0.f, nbp = 0.f;
  bool tin = false;
#pragma unroll
  for (int k = 0; k < 6; k++) {
    int idx = topi[m * 6 + k]; float v = topv[m * 6 + k];
    float p = expf(v - lse);
    if (idx == tgt) { tin = true; beta += (lse - v); Ps += p; }
    else if (recip[m * 6 + k]) { beta += 0.5f * (lse - v); Ps += p; nbp += p; }
  }
  if (!tin) { beta += (lse - tl); Ps += expf(tl - lse); }
  float alpha = 9.2103404f * (1.f - Ps) + 0.6931472f * nbp;
  __shared__ float sA[256], sB2[256];
  sA[m] = alpha; sB2[m] = beta;
  __syncthreads();
  for (int s = 128; s > 0; s >>= 1) {
    if (m < s) { sA[m] += sA[m + s]; sB2[m] += sB2[m + s]; }
    __syncthreads();
  }
  if (m == 0) { out[0] = 0.05f * sA[0] / 256.f; out[1] = sB2[0] / 256.f; }
}

extern "C" void kernel_launch(void* const* d_in, const int* in_sizes, int n_in,
                              void* d_out, int out_size, void* d_ws, size_t ws_size,
                              hipStream_t stream) {
  const float* x = (const float*)d_in[0];
  const float* em = (const float*)d_in[1];
  const int* targets = (const int*)d_in[2];
  char* ws = (char*)d_ws;
  unsigned short* em_bf = (unsigned short*)ws;                 // 67108864 B
  unsigned short* x_bf  = (unsigned short*)(ws + 67108864);    // 1048576 B
  float* logits = (float*)(ws + 68157440);                     // 16777216 B
  float* part6  = (float*)(ws + 84934656);                     // 4718592 B
  float* topv   = (float*)(ws + 89653248);                     // 6144 B
  int*   topi   = (int*)  (ws + 89659392);                     // 6144 B
  float* lse    = (float*)(ws + 89665536);                     // 1024 B
  float* sa     = (float*)(ws + 89666560);                     // 6144 B
  int*   recip  = (int*)  (ws + 89672704);                     // 6144 B

  cvt_kernel<<<dim3(32768), dim3(256), 0, stream>>>(em, em_bf, NEMB * DIMK / 4);
  cvt_kernel<<<dim3(512), dim3(256), 0, stream>>>(x, x_bf, NB * DIMK / 4);
  gemm_kernel<0><<<dim3(128, 2), dim3(256), 0, stream>>>(x_bf, em_bf, (const int*)nullptr,
                                                         logits, (float*)nullptr);
  rowstats_kernel<<<dim3(256), dim3(256), 0, stream>>>(logits, topv, topi, lse);
  sa_kernel<<<dim3(384), dim3(256), 0, stream>>>(em, topi, sa);
  gemm_kernel<1><<<dim3(128, 12), dim3(256), 0, stream>>>(em_bf, em_bf, topi,
                                                          (float*)nullptr, part6);
  stage2_kernel<<<dim3(6), dim3(256), 0, stream>>>(part6, sa, recip);
  final_kernel<<<dim3(1), dim3(256), 0, stream>>>(logits, topv, topi, lse, recip, targets,
                                                  (float*)d_out);
}

// Round 2
// 622.454 us; speedup vs baseline: 1.3113x; 1.3113x over previous
//
#include <hip/hip_runtime.h>
#include <math.h>

#define DIMK 2048
#define NEMB 16384
#define NB 256
#define NR2 1536          // 256*6 neighbor rows
#define NBLK 128          // n-blocks in sims gemm
#define INV_BETA 20.0f
#define NEG_INF (-3.0e38f)

typedef short short8 __attribute__((ext_vector_type(8)));
typedef float f32x4 __attribute__((ext_vector_type(4)));
typedef const __attribute__((address_space(1))) unsigned int* gas_ptr;
typedef __attribute__((address_space(3))) unsigned int* las_ptr;

__device__ __forceinline__ void gl_lds16(const void* g, void* l) {
  __builtin_amdgcn_global_load_lds((gas_ptr)g, (las_ptr)l, 16, 0, 0);
}

__device__ __forceinline__ unsigned short f2bf(float f) {
  unsigned u = __float_as_uint(f);
  u += 0x7fffu + ((u >> 16) & 1u);
  return (unsigned short)(u >> 16);
}

__device__ __forceinline__ void ins6(float x, float v[6]) {
  if (x > v[5]) {
    v[5] = x;
#pragma unroll
    for (int j = 5; j > 0; j--) {
      if (v[j] > v[j - 1]) { float tmp = v[j]; v[j] = v[j - 1]; v[j - 1] = tmp; }
    }
  }
}

__global__ __launch_bounds__(256) void cvt_kernel(const float* __restrict__ src,
                                                  unsigned short* __restrict__ dst, int n4) {
  int i = blockIdx.x * 256 + threadIdx.x;
  if (i < n4) {
    float4 f = ((const float4*)src)[i];
    ushort4 o;
    o.x = f2bf(f.x); o.y = f2bf(f.y); o.z = f2bf(f.z); o.w = f2bf(f.w);
    ((ushort4*)dst)[i] = o;
  }
}

// LDS: staging is 16 subtiles max; each subtile = 16 rows x 32 k of bf16, stored
// fragment-contiguous: chunk for (row=lane&15, kseg=lane>>4) at byte offset lane*16.
// MFMA fragment ds_read_b128 is then base + lane*16 -> fully contiguous, conflict-free.
union SMemT {
  unsigned short st[16 * 512];                      // 16 KB staging (A then B subtiles)
  struct { float ct[64 * 132]; float p6[64 * 24]; } ep;  // MODE1 epilogue ~40 KB
};

// MODE 0: C = X(256xK) * em^T -> logits*20 (fp32 out). tile 64(M)x128(N), grid (128,4)
// MODE 1: C = em[nidx](1536xK) * em^T -> per-(row,128col-block) top-6 partials. tile 128x128
template <int MODE>
__global__ __launch_bounds__(256, 2) void gemm_kernel(
    const unsigned short* __restrict__ Abase, const unsigned short* __restrict__ Bbase,
    const int* __restrict__ nidx, float* __restrict__ outC, float* __restrict__ part6) {
  constexpr int MTILE = (MODE == 0) ? 64 : 128;
  constexpr int MI = 4;
  constexpr int NI = (MODE == 0) ? 2 : 4;
  constexpr int NSUB_A = MTILE / 16;   // 4 or 8
  constexpr int NSUB = NSUB_A + 8;     // 12 or 16
  constexpr int NA = NSUB / 4;         // 3 or 4 staging DMAs per wave per k-iter

  __shared__ SMemT sm;
  __shared__ int rowIdxSh[128];
  int t = threadIdx.x;
  int lane = t & 63, wave = t >> 6;
  int quad = lane >> 4, l16 = lane & 15;
  int wr = (MODE == 0) ? 0 : (wave >> 1);
  int wc = (MODE == 0) ? wave : (wave & 1);
  int bn = blockIdx.x, bm = blockIdx.y;

  if constexpr (MODE == 1) {
    if (t < 128) rowIdxSh[t] = nidx[bm * 128 + t];
  }
  __syncthreads();

  // Precompute per-lane global source pointers for each staging assignment.
  const unsigned short* agp[NA];
  unsigned short* ldst[NA];
  {
    int seg = lane >> 4;
#pragma unroll
    for (int a = 0; a < NA; a++) {
      int s = wave + a * 4;
      const unsigned short* basep;
      size_t goff;
      if (s < NSUB_A) {
        int r = s * 16 + l16;
        int grow = (MODE == 0) ? (bm * MTILE + r) : rowIdxSh[r];
        basep = Abase;
        goff = (size_t)grow * DIMK;
      } else {
        int r = (s - NSUB_A) * 16 + l16;
        basep = Bbase;
        goff = (size_t)(bn * 128 + r) * DIMK;
      }
      agp[a] = basep + goff + seg * 8;
      ldst[a] = &sm.st[s * 512];      // wave-uniform LDS base
    }
  }

  f32x4 acc[MI][NI];
#pragma unroll
  for (int mi = 0; mi < MI; mi++)
#pragma unroll
    for (int ni = 0; ni < NI; ni++) acc[mi][ni] = (f32x4)0.0f;

  int lo = lane * 8;  // shorts: lane*16 bytes
  for (int k0 = 0; k0 < DIMK; k0 += 32) {
    __syncthreads();   // previous iter's fragment reads complete
#pragma unroll
    for (int a = 0; a < NA; a++) gl_lds16(agp[a] + k0, ldst[a]);
    __syncthreads();   // drains vmcnt -> staged data visible
    short8 af[MI], bfv[NI];
#pragma unroll
    for (int mi = 0; mi < MI; mi++)
      af[mi] = *(const short8*)&sm.st[(wr * MI + mi) * 512 + lo];
#pragma unroll
    for (int ni = 0; ni < NI; ni++)
      bfv[ni] = *(const short8*)&sm.st[(NSUB_A + wc * NI + ni) * 512 + lo];
#pragma unroll
    for (int mi = 0; mi < MI; mi++)
#pragma unroll
      for (int ni = 0; ni < NI; ni++)
        acc[mi][ni] = __builtin_amdgcn_mfma_f32_16x16x32_bf16(af[mi], bfv[ni], acc[mi][ni], 0, 0, 0);
  }

  if constexpr (MODE == 0) {
#pragma unroll
    for (int mi = 0; mi < MI; mi++) {
      int row = bm * MTILE + mi * 16 + quad * 4;
#pragma unroll
      for (int ni = 0; ni < NI; ni++) {
        int col = bn * 128 + wave * 32 + ni * 16 + l16;
#pragma unroll
        for (int rr = 0; rr < 4; rr++)
          outC[(size_t)(row + rr) * NEMB + col] = acc[mi][ni][rr] * INV_BETA;
      }
    }
  } else {
    __syncthreads();  // all LDS staging reads done before union reuse
#pragma unroll
    for (int ph = 0; ph < 2; ph++) {
      if (wr == ph) {
#pragma unroll
        for (int mi = 0; mi < 4; mi++)
#pragma unroll
          for (int ni = 0; ni < 4; ni++)
#pragma unroll
            for (int rr = 0; rr < 4; rr++)
              sm.ep.ct[(mi * 16 + quad * 4 + rr) * 132 + wc * 64 + ni * 16 + l16] = acc[mi][ni][rr];
      }
      __syncthreads();
      {
        int srow = t >> 2, sseg = t & 3;
        float v[6] = {NEG_INF, NEG_INF, NEG_INF, NEG_INF, NEG_INF, NEG_INF};
        const float* basep = &sm.ep.ct[srow * 132 + sseg * 32];
        for (int i = 0; i < 32; i++) ins6(basep[i], v);
#pragma unroll
        for (int j = 0; j < 6; j++) sm.ep.p6[srow * 24 + sseg * 6 + j] = v[j];
      }
      __syncthreads();
      if (t < 64) {
        float v[6] = {NEG_INF, NEG_INF, NEG_INF, NEG_INF, NEG_INF, NEG_INF};
        const float* pp = &sm.ep.p6[t * 24];
        for (int i = 0; i < 24; i++) ins6(pp[i], v);
        int rg = bm * 128 + ph * 64 + t;
        float* dst = part6 + ((size_t)rg * NBLK + bn) * 6;
#pragma unroll
        for (int j = 0; j < 6; j++) dst[j] = v[j];
      }
      __syncthreads();
    }
  }
}

__global__ __launch_bounds__(256) void rowstats_kernel(
    const float* __restrict__ logits, float* __restrict__ topv,
    int* __restrict__ topi, float* __restrict__ lse) {
  int m = blockIdx.x, t = threadIdx.x;
  const float* row = logits + (size_t)m * NEMB;
  __shared__ float sv[256];
  __shared__ int si[256];
  int chosen[6]; float chv[6];
  for (int pass = 0; pass < 6; pass++) {
    float bv = NEG_INF; int bi = 0x7fffffff;
    for (int i = t; i < NEMB; i += 256) {
      bool skip = false;
#pragma unroll
      for (int j = 0; j < 6; j++)
        if (j < pass && i == chosen[j]) skip = true;
      float v = row[i];
      if (!skip && (v > bv || (v == bv && i < bi))) { bv = v; bi = i; }
    }
    sv[t] = bv; si[t] = bi;
    __syncthreads();
    for (int s = 128; s > 0; s >>= 1) {
      if (t < s) {
        if (sv[t + s] > sv[t] || (sv[t + s] == sv[t] && si[t + s] < si[t])) {
          sv[t] = sv[t + s]; si[t] = si[t + s];
        }
      }
      __syncthreads();
    }
    chosen[pass] = si[0]; chv[pass] = sv[0];
    __syncthreads();
  }
  float mx = chv[0];
  float ssum = 0.f;
  for (int i = t; i < NEMB; i += 256) ssum += expf(row[i] - mx);
  sv[t] = ssum; __syncthreads();
  for (int s = 128; s > 0; s >>= 1) { if (t < s) sv[t] += sv[t + s]; __syncthreads(); }
  if (t == 0) {
    lse[m] = mx + logf(sv[0]);
#pragma unroll
    for (int j = 0; j < 6; j++) { topv[m * 6 + j] = chv[j]; topi[m * 6 + j] = chosen[j]; }
  }
}

// exact fp32 dot: sa[r] = em[topi[r]] . em[anchor(m=r/6)]
__global__ __launch_bounds__(256) void sa_kernel(const float* __restrict__ em,
                                                 const int* __restrict__ topi,
                                                 float* __restrict__ sa) {
  int gid = blockIdx.x * 256 + threadIdx.x;
  int w = gid >> 6, lane = gid & 63;
  if (w >= NR2) return;
  int m = w / 6;
  int i = topi[w], a = topi[m * 6];
  const float* ei = em + (size_t)i * DIMK;
  const float* ea = em + (size_t)a * DIMK;
  float s = 0.f;
  for (int d = lane; d < DIMK; d += 64) s += ei[d] * ea[d];
#pragma unroll
  for (int off = 32; off > 0; off >>= 1) s += __shfl_down(s, off, 64);
  if (lane == 0) sa[w] = s;
}

// recip[r] = 1 iff anchor-sim >= 6th-largest of sims row r.
// Equivalent: count of partial-top6 values strictly greater than sa < 6.
__global__ __launch_bounds__(256) void stage2_kernel(const float* __restrict__ part6,
                                                     const float* __restrict__ sa,
                                                     int* __restrict__ recip) {
  int gid = blockIdx.x * 256 + threadIdx.x;
  int w = gid >> 6, lane = gid & 63;
  if (w >= NR2) return;
  float s = sa[w];
  const float* p = part6 + (size_t)w * (NBLK * 6);
  int cnt = 0;
  for (int i = lane; i < NBLK * 6; i += 64) cnt += (p[i] > s) ? 1 : 0;
#pragma unroll
  for (int off = 32; off > 0; off >>= 1) cnt += __shfl_down(cnt, off, 64);
  if (lane == 0) recip[w] = (cnt < 6) ? 1 : 0;
}

__global__ __launch_bounds__(256) void final_kernel(
    const float* __restrict__ logits, const float* __restrict__ topv,
    const int* __restrict__ topi, const float* __restrict__ lse_arr,
    const int* __restrict__ recip, const int* __restrict__ targets,
    float* __restrict__ out) {
  int m = threadIdx.x;
  float lse = lse_arr[m];
  int tgt = targets[m];
  float tl = logits[(size_t)m * NEMB + tgt];
  float beta = 0.f, Ps = 0.f, nbp = 0.f;
  bool tin = false;
#pragma unroll
  for (int k = 0; k < 6; k++) {
    int idx = topi[m * 6 + k]; float v = topv[m * 6 + k];
    float p = expf(v - lse);
    if (idx == tgt) { tin = true; beta += (lse - v); Ps += p; }
    else if (recip[m * 6 + k]) { beta += 0.5f * (lse - v); Ps += p; nbp += p; }
  }
  if (!tin) { beta += (lse - tl); Ps += expf(tl - lse); }
  float alpha = 9.2103404f * (1.f - Ps) + 0.6931472f * nbp;
  __shared__ float sA[256], sB2[256];
  sA[m] = alpha; sB2[m] = beta;
  __syncthreads();
  for (int s = 128; s > 0; s >>= 1) {
    if (m < s) { sA[m] += sA[m + s]; sB2[m] += sB2[m + s]; }
    __syncthreads();
  }
  if (m == 0) { out[0] = 0.05f * sA[0] / 256.f; out[1] = sB2[0] / 256.f; }
}

extern "C" void kernel_launch(void* const* d_in, const int* in_sizes, int n_in,
                              void* d_out, int out_size, void* d_ws, size_t ws_size,
                              hipStream_t stream) {
  const float* x = (const float*)d_in[0];
  const float* em = (const float*)d_in[1];
  const int* targets = (const int*)d_in[2];
  char* ws = (char*)d_ws;
  unsigned short* em_bf = (unsigned short*)ws;                 // 67108864 B
  unsigned short* x_bf  = (unsigned short*)(ws + 67108864);    // 1048576 B
  float* logits = (float*)(ws + 68157440);                     // 16777216 B
  float* part6  = (float*)(ws + 84934656);                     // 4718592 B
  float* topv   = (float*)(ws + 89653248);                     // 6144 B
  int*   topi   = (int*)  (ws + 89659392);                     // 6144 B
  float* lse    = (float*)(ws + 89665536);                     // 1024 B
  float* sa     = (float*)(ws + 89666560);                     // 6144 B
  int*   recip  = (int*)  (ws + 89672704);                     // 6144 B

  cvt_kernel<<<dim3(32768), dim3(256), 0, stream>>>(em, em_bf, NEMB * DIMK / 4);
  cvt_kernel<<<dim3(512), dim3(256), 0, stream>>>(x, x_bf, NB * DIMK / 4);
  gemm_kernel<0><<<dim3(128, 4), dim3(256), 0, stream>>>(x_bf, em_bf, (const int*)nullptr,
                                                         logits, (float*)nullptr);
  rowstats_kernel<<<dim3(256), dim3(256), 0, stream>>>(logits, topv, topi, lse);
  sa_kernel<<<dim3(384), dim3(256), 0, stream>>>(em, topi, sa);
  gemm_kernel<1><<<dim3(128, 12), dim3(256), 0, stream>>>(em_bf, em_bf, topi,
                                                          (float*)nullptr, part6);
  stage2_kernel<<<dim3(384), dim3(256), 0, stream>>>(part6, sa, recip);
  final_kernel<<<dim3(1), dim3(256), 0, stream>>>(logits, topv, topi, lse, recip, targets,
                                                  (float*)d_out);
}

// Round 3
// 615.041 us; speedup vs baseline: 1.3271x; 1.0121x over previous
//
#include <hip/hip_runtime.h>
#include <math.h>

#define DIMK 2048
#define NEMB 16384
#define NB 256
#define NR2 1536          // 256*6 neighbor rows
#define NBLK 128          // n-blocks in sims gemm
#define INV_BETA 20.0f
#define NEG_INF (-3.0e38f)

typedef short short8 __attribute__((ext_vector_type(8)));
typedef float f32x4 __attribute__((ext_vector_type(4)));
typedef const __attribute__((address_space(1))) unsigned int* gas_ptr;
typedef __attribute__((address_space(3))) unsigned int* las_ptr;

__device__ __forceinline__ void gl_lds16(const void* g, void* l) {
  __builtin_amdgcn_global_load_lds((gas_ptr)g, (las_ptr)l, 16, 0, 0);
}

__device__ __forceinline__ unsigned short f2bf(float f) {
  unsigned u = __float_as_uint(f);
  u += 0x7fffu + ((u >> 16) & 1u);
  return (unsigned short)(u >> 16);
}

__device__ __forceinline__ void ins6(float x, float v[6]) {
  if (x > v[5]) {
    v[5] = x;
#pragma unroll
    for (int j = 5; j > 0; j--) {
      if (v[j] > v[j - 1]) { float tmp = v[j]; v[j] = v[j - 1]; v[j - 1] = tmp; }
    }
  }
}

// top-6 insert with (value desc, index asc) tie-break — matches jax top_k order
__device__ __forceinline__ void ins6i(float x, int xi, float v[6], int vi[6]) {
  if (x > v[5] || (x == v[5] && xi < vi[5])) {
    v[5] = x; vi[5] = xi;
#pragma unroll
    for (int j = 5; j > 0; j--) {
      if (v[j] > v[j - 1] || (v[j] == v[j - 1] && vi[j] < vi[j - 1])) {
        float tv = v[j]; v[j] = v[j - 1]; v[j - 1] = tv;
        int ti = vi[j]; vi[j] = vi[j - 1]; vi[j - 1] = ti;
      }
    }
  }
}

__global__ __launch_bounds__(256) void cvt_kernel(const float* __restrict__ src,
                                                  unsigned short* __restrict__ dst, int n4) {
  int i = blockIdx.x * 256 + threadIdx.x;
  if (i < n4) {
    float4 f = ((const float4*)src)[i];
    ushort4 o;
    o.x = f2bf(f.x); o.y = f2bf(f.y); o.z = f2bf(f.z); o.w = f2bf(f.w);
    ((ushort4*)dst)[i] = o;
  }
}

// Staging: 16 subtiles of [16 rows x 32 k] bf16 (1 KB each), fragment-contiguous:
// chunk for (row=lane&15, kseg=lane>>4) at byte offset lane*16 -> conflict-free b128.
// Epilogue (MODE1): ct stride 133 (5 coprime 32 -> <=2-way), p6 stride 49 (17 coprime 32).
union SMemT {
  unsigned short st[16 * 512];                           // 16 KB staging
  struct { float ct[32 * 133]; float p6[32 * 49]; } ep;  // 23.3 KB epilogue
};

// MODE 0: C = X(256xK) * em^T -> logits*20 (fp32 out). tile 64(M)x128(N), grid (128,4)
// MODE 1: C = em[nidx](1536xK) * em^T -> per-(row,128col-block) top-6 partials. tile 128x128
template <int MODE>
__global__ __launch_bounds__(256, 4) void gemm_kernel(
    const unsigned short* __restrict__ Abase, const unsigned short* __restrict__ Bbase,
    const int* __restrict__ nidx, float* __restrict__ outC, float* __restrict__ part6) {
  constexpr int MTILE = (MODE == 0) ? 64 : 128;
  constexpr int MI = 4;
  constexpr int NI = (MODE == 0) ? 2 : 4;
  constexpr int NSUB_A = MTILE / 16;   // 4 or 8
  constexpr int NSUB = NSUB_A + 8;     // 12 or 16
  constexpr int NA = NSUB / 4;         // 3 or 4 staging DMAs per wave per k-iter

  __shared__ SMemT sm;
  __shared__ int rowIdxSh[128];
  int t = threadIdx.x;
  int lane = t & 63, wave = t >> 6;
  int quad = lane >> 4, l16 = lane & 15;
  int wr = (MODE == 0) ? 0 : (wave >> 1);
  int wc = (MODE == 0) ? wave : (wave & 1);
  int bn = blockIdx.x, bm = blockIdx.y;

  if constexpr (MODE == 1) {
    if (t < 128) rowIdxSh[t] = nidx[bm * 128 + t];
  }
  __syncthreads();

  const unsigned short* agp[NA];
  unsigned short* ldst[NA];
  {
    int seg = lane >> 4;
#pragma unroll
    for (int a = 0; a < NA; a++) {
      int s = wave + a * 4;
      const unsigned short* basep;
      size_t goff;
      if (s < NSUB_A) {
        int r = s * 16 + l16;
        int grow = (MODE == 0) ? (bm * MTILE + r) : rowIdxSh[r];
        basep = Abase;
        goff = (size_t)grow * DIMK;
      } else {
        int r = (s - NSUB_A) * 16 + l16;
        basep = Bbase;
        goff = (size_t)(bn * 128 + r) * DIMK;
      }
      agp[a] = basep + goff + seg * 8;
      ldst[a] = &sm.st[s * 512];      // wave-uniform LDS base
    }
  }

  f32x4 acc[MI][NI];
#pragma unroll
  for (int mi = 0; mi < MI; mi++)
#pragma unroll
    for (int ni = 0; ni < NI; ni++) acc[mi][ni] = (f32x4)0.0f;

  int lo = lane * 8;  // shorts: lane*16 bytes
  for (int k0 = 0; k0 < DIMK; k0 += 32) {
    __syncthreads();   // previous iter's fragment reads complete
#pragma unroll
    for (int a = 0; a < NA; a++) gl_lds16(agp[a] + k0, ldst[a]);
    __syncthreads();   // drains vmcnt -> staged data visible
    short8 af[MI], bfv[NI];
#pragma unroll
    for (int mi = 0; mi < MI; mi++)
      af[mi] = *(const short8*)&sm.st[(wr * MI + mi) * 512 + lo];
#pragma unroll
    for (int ni = 0; ni < NI; ni++)
      bfv[ni] = *(const short8*)&sm.st[(NSUB_A + wc * NI + ni) * 512 + lo];
#pragma unroll
    for (int mi = 0; mi < MI; mi++)
#pragma unroll
      for (int ni = 0; ni < NI; ni++)
        acc[mi][ni] = __builtin_amdgcn_mfma_f32_16x16x32_bf16(af[mi], bfv[ni], acc[mi][ni], 0, 0, 0);
  }

  if constexpr (MODE == 0) {
#pragma unroll
    for (int mi = 0; mi < MI; mi++) {
      int row = bm * MTILE + mi * 16 + quad * 4;
#pragma unroll
      for (int ni = 0; ni < NI; ni++) {
        int col = bn * 128 + wave * 32 + ni * 16 + l16;
#pragma unroll
        for (int rr = 0; rr < 4; rr++)
          outC[(size_t)(row + rr) * NEMB + col] = acc[mi][ni][rr] * INV_BETA;
      }
    }
  } else {
    __syncthreads();  // all LDS staging reads done before union reuse
#pragma unroll
    for (int ph = 0; ph < 4; ph++) {       // 32 tile-rows per phase
      int phwr = ph >> 1, phmi0 = (ph & 1) * 2;
      if (wr == phwr) {
#pragma unroll
        for (int mi2 = 0; mi2 < 2; mi2++) {
          int mi = phmi0 + mi2;
#pragma unroll
          for (int ni = 0; ni < 4; ni++)
#pragma unroll
            for (int rr = 0; rr < 4; rr++)
              sm.ep.ct[(mi2 * 16 + quad * 4 + rr) * 133 + wc * 64 + ni * 16 + l16] =
                  acc[mi][ni][rr];
        }
      }
      __syncthreads();
      {
        int srow = t & 31, sseg = t >> 5;   // 8 segs x 16 cols
        float v[6] = {NEG_INF, NEG_INF, NEG_INF, NEG_INF, NEG_INF, NEG_INF};
        const float* basep = &sm.ep.ct[srow * 133 + sseg * 16];
#pragma unroll
        for (int i = 0; i < 16; i++) ins6(basep[i], v);
#pragma unroll
        for (int j = 0; j < 6; j++) sm.ep.p6[srow * 49 + sseg * 6 + j] = v[j];
      }
      __syncthreads();
      if (t < 32) {
        float v[6] = {NEG_INF, NEG_INF, NEG_INF, NEG_INF, NEG_INF, NEG_INF};
        const float* pp = &sm.ep.p6[t * 49];
        for (int i = 0; i < 48; i++) ins6(pp[i], v);
        int rg = bm * 128 + ph * 32 + t;
        float* dst = part6 + ((size_t)rg * NBLK + bn) * 6;
#pragma unroll
        for (int j = 0; j < 6; j++) dst[j] = v[j];
      }
      __syncthreads();
    }
  }
}

// single-pass: per-thread top6(v,i) + online (max,sumexp), then LDS tree merge
__global__ __launch_bounds__(256) void rowstats_kernel(
    const float* __restrict__ logits, float* __restrict__ topv,
    int* __restrict__ topi, float* __restrict__ lse) {
  int m = blockIdx.x, t = threadIdx.x;
  const float* row = logits + (size_t)m * NEMB;
  float v6[6]; int i6[6];
#pragma unroll
  for (int j = 0; j < 6; j++) { v6[j] = NEG_INF; i6[j] = 0x7fffffff; }
  float mx = NEG_INF, sme = 0.f;
  for (int i = t; i < NEMB; i += 256) {
    float v = row[i];
    if (v > mx) { sme = sme * expf(mx - v) + 1.f; mx = v; }
    else sme += expf(v - mx);
    ins6i(v, i, v6, i6);
  }
  __shared__ float sv[256 * 6]; __shared__ int si[256 * 6];
  __shared__ float smx[256], ssm[256];
#pragma unroll
  for (int j = 0; j < 6; j++) { sv[t * 6 + j] = v6[j]; si[t * 6 + j] = i6[j]; }
  smx[t] = mx; ssm[t] = sme;
  __syncthreads();
  for (int s = 128; s > 0; s >>= 1) {
    if (t < s) {
      float mo = smx[t + s], lo = ssm[t + s];
      float mn = fmaxf(smx[t], mo);
      ssm[t] = ssm[t] * expf(smx[t] - mn) + lo * expf(mo - mn);
      smx[t] = mn;
#pragma unroll
      for (int j = 0; j < 6; j++) ins6i(sv[(t + s) * 6 + j], si[(t + s) * 6 + j], v6, i6);
#pragma unroll
      for (int j = 0; j < 6; j++) { sv[t * 6 + j] = v6[j]; si[t * 6 + j] = i6[j]; }
    }
    __syncthreads();
  }
  if (t == 0) {
    lse[m] = smx[0] + logf(ssm[0]);
#pragma unroll
    for (int j = 0; j < 6; j++) { topv[m * 6 + j] = v6[j]; topi[m * 6 + j] = i6[j]; }
  }
}

// exact fp32 dot: sa[r] = em[topi[r]] . em[anchor(m=r/6)]
__global__ __launch_bounds__(256) void sa_kernel(const float* __restrict__ em,
                                                 const int* __restrict__ topi,
                                                 float* __restrict__ sa) {
  int gid = blockIdx.x * 256 + threadIdx.x;
  int w = gid >> 6, lane = gid & 63;
  if (w >= NR2) return;
  int m = w / 6;
  int i = topi[w], a = topi[m * 6];
  const float* ei = em + (size_t)i * DIMK;
  const float* ea = em + (size_t)a * DIMK;
  float s = 0.f;
  for (int d = lane; d < DIMK; d += 64) s += ei[d] * ea[d];
#pragma unroll
  for (int off = 32; off > 0; off >>= 1) s += __shfl_down(s, off, 64);
  if (lane == 0) sa[w] = s;
}

// recip[r] = 1 iff anchor-sim >= 6th-largest of sims row r
// == (count of partial-top6 values strictly greater than sa) < 6
__global__ __launch_bounds__(256) void stage2_kernel(const float* __restrict__ part6,
                                                     const float* __restrict__ sa,
                                                     int* __restrict__ recip) {
  int gid = blockIdx.x * 256 + threadIdx.x;
  int w = gid >> 6, lane = gid & 63;
  if (w >= NR2) return;
  float s = sa[w];
  const float* p = part6 + (size_t)w * (NBLK * 6);
  int cnt = 0;
  for (int i = lane; i < NBLK * 6; i += 64) cnt += (p[i] > s) ? 1 : 0;
#pragma unroll
  for (int off = 32; off > 0; off >>= 1) cnt += __shfl_down(cnt, off, 64);
  if (lane == 0) recip[w] = (cnt < 6) ? 1 : 0;
}

__global__ __launch_bounds__(256) void final_kernel(
    const float* __restrict__ logits, const float* __restrict__ topv,
    const int* __restrict__ topi, const float* __restrict__ lse_arr,
    const int* __restrict__ recip, const int* __restrict__ targets,
    float* __restrict__ out) {
  int m = threadIdx.x;
  float lse = lse_arr[m];
  int tgt = targets[m];
  float tl = logits[(size_t)m * NEMB + tgt];
  float beta = 0.f, Ps = 0.f, nbp = 0.f;
  bool tin = false;
#pragma unroll
  for (int k = 0; k < 6; k++) {
    int idx = topi[m * 6 + k]; float v = topv[m * 6 + k];
    float p = expf(v - lse);
    if (idx == tgt) { tin = true; beta += (lse - v); Ps += p; }
    else if (recip[m * 6 + k]) { beta += 0.5f * (lse - v); Ps += p; nbp += p; }
  }
  if (!tin) { beta += (lse - tl); Ps += expf(tl - lse); }
  float alpha = 9.2103404f * (1.f - Ps) + 0.6931472f * nbp;
  __shared__ float sA[256], sB2[256];
  sA[m] = alpha; sB2[m] = beta;
  __syncthreads();
  for (int s = 128; s > 0; s >>= 1) {
    if (m < s) { sA[m] += sA[m + s]; sB2[m] += sB2[m + s]; }
    __syncthreads();
  }
  if (m == 0) { out[0] = 0.05f * sA[0] / 256.f; out[1] = sB2[0] / 256.f; }
}

extern "C" void kernel_launch(void* const* d_in, const int* in_sizes, int n_in,
                              void* d_out, int out_size, void* d_ws, size_t ws_size,
                              hipStream_t stream) {
  const float* x = (const float*)d_in[0];
  const float* em = (const float*)d_in[1];
  const int* targets = (const int*)d_in[2];
  char* ws = (char*)d_ws;
  unsigned short* em_bf = (unsigned short*)ws;                 // 67108864 B
  unsigned short* x_bf  = (unsigned short*)(ws + 67108864);    // 1048576 B
  float* logits = (float*)(ws + 68157440);                     // 16777216 B
  float* part6  = (float*)(ws + 84934656);                     // 4718592 B
  float* topv   = (float*)(ws + 89653248);                     // 6144 B
  int*   topi   = (int*)  (ws + 89659392);                     // 6144 B
  float* lse    = (float*)(ws + 89665536);                     // 1024 B
  float* sa     = (float*)(ws + 89666560);                     // 6144 B
  int*   recip  = (int*)  (ws + 89672704);                     // 6144 B

  cvt_kernel<<<dim3(32768), dim3(256), 0, stream>>>(em, em_bf, NEMB * DIMK / 4);
  cvt_kernel<<<dim3(512), dim3(256), 0, stream>>>(x, x_bf, NB * DIMK / 4);
  gemm_kernel<0><<<dim3(128, 4), dim3(256), 0, stream>>>(x_bf, em_bf, (const int*)nullptr,
                                                         logits, (float*)nullptr);
  rowstats_kernel<<<dim3(256), dim3(256), 0, stream>>>(logits, topv, topi, lse);
  sa_kernel<<<dim3(384), dim3(256), 0, stream>>>(em, topi, sa);
  gemm_kernel<1><<<dim3(128, 12), dim3(256), 0, stream>>>(em_bf, em_bf, topi,
                                                          (float*)nullptr, part6);
  stage2_kernel<<<dim3(384), dim3(256), 0, stream>>>(part6, sa, recip);
  final_kernel<<<dim3(1), dim3(256), 0, stream>>>(logits, topv, topi, lse, recip, targets,
                                                  (float*)d_out);
}